// Round 27
// baseline (554.387 us; speedup 1.0000x reference)
//
#include <hip/hip_runtime.h>
#include <cstdint>
#include <cstddef>

#define D_MODEL   768
#define D_STATE   64
#define D_INNER   1536
#define HEADDIM   64
#define NHEADS    24
#define D_CONV    4
#define CONV_DIM  1664      // D_INNER + 2*D_STATE
#define D_IN_PROJ 3224      // 2*D_INNER + 2*D_STATE + NHEADS
#define N_MERGED  6448      // 2 * D_IN_PROJ
#define BATCH     4
#define SEQLEN    2048
#define NROWS     (BATCH*SEQLEN)   // 8192
#define NCHUNK    32
#define Q         64               // chunk length
#define HLOC_SZ   ((size_t)BATCH*NHEADS*NCHUNK*4096)   // per dir, u16

typedef unsigned short u16;
typedef __attribute__((ext_vector_type(8))) short bf16x8;
typedef __attribute__((ext_vector_type(8))) unsigned short u16x8;
typedef __attribute__((ext_vector_type(4))) float f32x4;

__device__ __forceinline__ int flip_row(int m, const int* __restrict__ lengths) {
    int b = m >> 11;
    int t = m & (SEQLEN - 1);
    int len = lengths[b];
    int ft = (t < len) ? (len - 1 - t) : t;
    return (b << 11) | ft;
}

__device__ __forceinline__ u16 f2bf(float f) {
    unsigned int u = __float_as_uint(f);
    unsigned int r = u + 0x7FFFu + ((u >> 16) & 1u);
    return (u16)(r >> 16);
}
__device__ __forceinline__ float bf2f(u16 h) {
    return __uint_as_float(((unsigned int)h) << 16);
}

// async global->LDS DMA, 16B per lane. LDS dest is wave-uniform base + lane*16;
// per-lane global src carries the inverse swizzle (guide caveat #21).
typedef const __attribute__((address_space(1))) unsigned int gu32;
typedef __attribute__((address_space(3))) unsigned int lu32;
__device__ __forceinline__ void gload_lds16(const u16* g, u16* l) {
    __builtin_amdgcn_global_load_lds((gu32*)g, (lu32*)l, 16, 0, 0);
}

// XCD-aware bijective remap: each XCD owns a contiguous M-band (gy/8 y-tiles,
// A-tiles stay resident in its private L2) and walks x-outer / y-inner so each
// W-tile is fetched once per XCD. Requires gy % 8 == 0 (else identity).
__device__ __forceinline__ void xcd_remap(int& bx, int& by) {
    const int gx = gridDim.x, gy = gridDim.y;
    if ((gy & 7) != 0) return;
    const int yband = gy >> 3;
    int flat = by * gx + bx;
    int xcd = flat & 7;
    int pos = flat >> 3;
    bx = pos / yband;
    by = xcd * yband + (pos % yband);
}

// f32 -> single bf16 array
__global__ __launch_bounds__(256)
void convert_single_kernel(const float* __restrict__ in, u16* __restrict__ hi, int n4)
{
    int i = blockIdx.x * 256 + threadIdx.x;
    if (i >= n4) return;
    float4 v = *(const float4*)(in + (size_t)i * 4);
    ushort4 h;
    h.x = f2bf(v.x); h.y = f2bf(v.y); h.z = f2bf(v.z); h.w = f2bf(v.w);
    *(ushort4*)(hi + (size_t)i * 4) = h;
}

// merged prep: (a) op_w (768x1536) -> single bf16, (b) transpose BOTH out_w
// matrices (768x1536 -> owT_d[1536][768] single bf16)
#define NCONV_BLK 1152    // 768*1536/4/256
#define NT_BLK    288     // 24 x 12 transpose tiles (per dir)
__global__ __launch_bounds__(256)
void prep_outw_kernel(const float* __restrict__ op_w,
                      const float* __restrict__ ow0, const float* __restrict__ ow1,
                      u16* __restrict__ oph, u16* __restrict__ owTb)
{
    const int bid = blockIdx.x;
    const int tid = threadIdx.x;
    if (bid < NCONV_BLK) {
        int i = bid * 256 + tid;
        float4 v = *(const float4*)(op_w + (size_t)i * 4);
        ushort4 h;
        h.x = f2bf(v.x); h.y = f2bf(v.y); h.z = f2bf(v.z); h.w = f2bf(v.w);
        *(ushort4*)(oph + (size_t)i * 4) = h;
        return;
    }
    __shared__ float T[64][65];
    const int t = bid - NCONV_BLK;
    const int dir = t / NT_BLK;
    const int tb  = t % NT_BLK;
    const float* ow = dir ? ow1 : ow0;
    u16* owTh = owTb + (size_t)dir * D_INNER * D_MODEL;
    const int e0 = (tb % 24) * 64;
    const int d0 = (tb / 24) * 64;
    const int col = tid & 63, rg = tid >> 6;
    #pragma unroll
    for (int i = 0; i < 16; i++) {
        int r = rg + i * 4;
        T[r][col] = ow[(size_t)(d0 + r) * D_INNER + e0 + col];
    }
    __syncthreads();
    const int er = tid >> 2, dc0 = (tid & 3) * 16;
    u16x8 ph[2];
    #pragma unroll
    for (int j = 0; j < 16; j++)
        ph[j >> 3][j & 7] = f2bf(T[dc0 + j][er]);
    size_t obase = (size_t)(e0 + er) * D_MODEL + d0 + dc0;
    *(u16x8*)(owTh + obase)     = ph[0];
    *(u16x8*)(owTh + obase + 8) = ph[1];
}

// ---------- single-bf16 MFMA GEMM, BK=32, DOUBLE-BUFFERED LDS ----------
// 128x128 tile, 256 threads = 4 waves (2x2), 4x4 16x16 frags/wave.
// Staging via global_load_lds (linear LDS dest, inverse-swizzled global src).
// mode 1: merged in_proj split store (N=6448)
// mode 4: Cp[m*ldc+nn] = bf16(acc); blockIdx.z==1 switches to (A2,W2,Cp2)
__global__ __launch_bounds__(256, 4)
void mfma_gemm(const u16* __restrict__ A, int lda,
               const u16* __restrict__ W, int ldw,
               int N, int K, const int* __restrict__ lengths, int mode,
               u16* __restrict__ z0, u16* __restrict__ xb0,
               u16* __restrict__ z1, u16* __restrict__ xb1,
               u16* __restrict__ Cp, int ldc,
               const u16* __restrict__ A2, const u16* __restrict__ W2,
               u16* __restrict__ Cp2)
{
    if (blockIdx.z == 1) { A = A2; W = W2; Cp = Cp2; }
    __shared__ alignas(16) u16 lds[2 * 2 * 4096];   // [buf][matrix][4096]
    const int tid = threadIdx.x;
    int bxr = blockIdx.x, byr = blockIdx.y;
    xcd_remap(bxr, byr);
    const int m0 = byr * 128;
    const int n0 = bxr * 128;
    const int lane = tid & 63;
    const int wid = tid >> 6;
    const int wm = wid >> 1, wn = wid & 1;

    // async-staging addressing: linear LDS slot (kh=wid, rsw=i*64+lane)
    // holds original row r = (rsw&0x78)|((rsw&7)^(wid<<1))  [XOR involution]
    int aoffs[2], woffs[2], ldsoff[2];
    #pragma unroll
    for (int i = 0; i < 2; i++) {
        int rsw = i * 64 + lane;
        int r = (rsw & 0x78) | ((rsw & 7) ^ ((wid << 1) & 7));
        aoffs[i] = (m0 + r) * lda + wid * 8;
        int wr = n0 + r; if (wr >= N) wr = N - 1;
        woffs[i] = wr * ldw + wid * 8;
        ldsoff[i] = wid * 1024 + i * 512;   // u16 units; wave-uniform
    }

    f32x4 acc[4][4];
    const f32x4 zero4 = {0.f, 0.f, 0.f, 0.f};
    #pragma unroll
    for (int i = 0; i < 4; i++)
        #pragma unroll
        for (int j = 0; j < 4; j++) acc[i][j] = zero4;

    const int l15 = lane & 15, lq = lane >> 4;
    const int arow0 = wm * 64 + l15;
    const int wrow0 = wn * 64 + l15;
    const int abase = lq * 1024 + ((arow0 & 0x78) | ((arow0 ^ (lq << 1)) & 7)) * 8;
    const int wbase = lq * 1024 + ((wrow0 & 0x78) | ((wrow0 ^ (lq << 1)) & 7)) * 8;

    // prologue: DMA tile 0 -> buf0
    #pragma unroll
    for (int i = 0; i < 2; i++) {
        gload_lds16(A + (size_t)aoffs[i], lds + 0 * 4096 + ldsoff[i]);
        gload_lds16(W + (size_t)woffs[i], lds + 1 * 4096 + ldsoff[i]);
    }
    __syncthreads();

    int cur = 0;
    for (int kt = 0; kt < K; kt += 32) {
        u16* Lc = lds + cur * 8192;
        if (kt + 32 < K) {
            u16* Ln = lds + (cur ^ 1) * 8192;
            #pragma unroll
            for (int i = 0; i < 2; i++) {
                gload_lds16(A + (size_t)aoffs[i] + kt + 32, Ln + 0 * 4096 + ldsoff[i]);
                gload_lds16(W + (size_t)woffs[i] + kt + 32, Ln + 1 * 4096 + ldsoff[i]);
            }
        }
        bf16x8 ah[4], wv[4];
        #pragma unroll
        for (int f = 0; f < 4; f++) {
            ah[f] = *(const bf16x8*)(Lc + 0 * 4096 + abase + f * 128);
            wv[f] = *(const bf16x8*)(Lc + 1 * 4096 + wbase + f * 128);
        }
        #pragma unroll
        for (int fr = 0; fr < 4; fr++)
            #pragma unroll
            for (int fc = 0; fc < 4; fc++)
                acc[fr][fc] = __builtin_amdgcn_mfma_f32_16x16x32_bf16(
                    ah[fr], wv[fc], acc[fr][fc], 0, 0, 0);
        __syncthreads();   // drains vmcnt (incl. global_load_lds) + barrier
        cur ^= 1;
    }

    #pragma unroll
    for (int fr = 0; fr < 4; fr++) {
        int mr[4], fm[4];
        #pragma unroll
        for (int r = 0; r < 4; r++) {
            mr[r] = m0 + wm * 64 + fr * 16 + lq * 4 + r;
            fm[r] = (mode == 1) ? flip_row(mr[r], lengths) : mr[r];
        }
        #pragma unroll
        for (int fc = 0; fc < 4; fc++) {
            const int nn0 = n0 + wn * 64 + fc * 16 + l15;
            if (nn0 >= N) continue;
            #pragma unroll
            for (int r = 0; r < 4; r++) {
                float v = acc[fr][fc][r];
                if (mode == 1) {
                    int nn = nn0;
                    if (nn < D_INNER)
                        z0[(size_t)mr[r] * D_INNER + nn] = f2bf(v);
                    else if (nn < D_INNER + CONV_DIM)
                        xb0[(size_t)mr[r] * CONV_DIM + (nn - D_INNER)] = f2bf(v);
                    else if (nn >= D_IN_PROJ) {
                        int l2 = nn - D_IN_PROJ;
                        if (l2 < D_INNER)
                            z1[(size_t)fm[r] * D_INNER + l2] = f2bf(v);
                        else if (l2 < D_INNER + CONV_DIM)
                            xb1[(size_t)fm[r] * CONV_DIM + (l2 - D_INNER)] = f2bf(v);
                        // dt cols of either dir: dt_exact covers
                    }
                } else {  // mode 4
                    Cp[(size_t)mr[r] * ldc + nn0] = f2bf(v);
                }
            }
        }
    }
}

// merged exact fp32 dt_raw for both dirs; also zeroes sqsum
// grid (2048, 2) x 256
__global__ __launch_bounds__(256)
void dt_exact_kernel(const float* __restrict__ x,
                     const float* __restrict__ wdt0, const float* __restrict__ wdt1,
                     const int* __restrict__ lengths,
                     float* __restrict__ la, float* __restrict__ sqsum)
{
    const int dir = blockIdx.y;
    const float* wdt = dir ? wdt1 : wdt0;
    float* lad = la + (size_t)dir * NROWS * NHEADS;
    float* sqd = sqsum + (size_t)dir * NROWS;
    const int wv = threadIdx.x >> 6, lane = threadIdx.x & 63;
    const int row = blockIdx.x * 4 + wv;
    int grow = dir ? flip_row(row, lengths) : row;
    const float* xr = x + (size_t)grow * D_MODEL;
    float xv[12];
    #pragma unroll
    for (int k = 0; k < 12; k++) xv[k] = xr[k * 64 + lane];
    if (lane == 1) sqd[row] = 0.f;
    for (int c = 0; c < NHEADS; c++) {
        const float* wr = wdt + (size_t)c * D_MODEL;
        float acc = 0.f;
        #pragma unroll
        for (int k = 0; k < 12; k++) acc = fmaf(xv[k], wr[k * 64 + lane], acc);
        #pragma unroll
        for (int o = 32; o > 0; o >>= 1) acc += __shfl_xor(acc, o);
        if (lane == 0) lad[(size_t)row * NHEADS + c] = acc;
    }
}

// merged conv + silu + per-chunk transpose + (cg==26) dt/cumsum; dir = blockIdx.z
__global__ __launch_bounds__(256)
void conv_silu_fused_kernel(const u16* __restrict__ xbcrb,
                            const float* __restrict__ cw0, const float* __restrict__ cw1,
                            const float* __restrict__ cb0, const float* __restrict__ cb1,
                            u16* __restrict__ xTb, u16* __restrict__ bcb,
                            const float* __restrict__ dtbias0, const float* __restrict__ dtbias1,
                            const float* __restrict__ alog0, const float* __restrict__ alog1,
                            float* __restrict__ dtbb, float* __restrict__ lab)
{
    const int dir = blockIdx.z;
    const u16* xbcr = xbcrb + (size_t)dir * NROWS * CONV_DIM;
    const float* cw = dir ? cw1 : cw0;
    const float* cb = dir ? cb1 : cb0;
    u16* xT = xTb + (size_t)dir * NROWS * D_INNER;
    u16* bc = bcb + (size_t)dir * NROWS * 128;
    const float* dt_bias = dir ? dtbias1 : dtbias0;
    const float* A_log   = dir ? alog1 : alog0;
    float* dtb = dtbb + (size_t)dir * NROWS * NHEADS;
    float* la  = lab  + (size_t)dir * NROWS * NHEADS;

    __shared__ float T[64][65];
    const int cg = blockIdx.x;
    const int rc = blockIdx.y;
    const int tid = threadIdx.x;
    if (cg == 26) {
        const int lane2 = tid & 63, w = tid >> 6;
        const int row0 = rc * 64;
        #pragma unroll
        for (int i = 0; i < 6; i++) {
            int h = w * 6 + i;
            size_t idx = (size_t)(row0 + lane2) * NHEADS + h;
            float v = la[idx] + dt_bias[h];
            float sp = (v > 20.f) ? v : log1pf(expf(v));
            dtb[idx] = sp;
            float dA = sp * (-expf(A_log[h]));
            #pragma unroll
            for (int o = 1; o < 64; o <<= 1) {
                float u = __shfl_up(dA, o);
                if (lane2 >= o) dA += u;
            }
            la[idx] = dA;
        }
        return;
    }
    const int col = tid & 63, rg = tid >> 6;
    const int c = cg * 64 + col;
    const int rstart = rc * 64 + rg * 16;
    const int t0 = rstart & (SEQLEN - 1);
    const float c0 = cw[c*4+0], c1 = cw[c*4+1], c2 = cw[c*4+2], c3 = cw[c*4+3];
    const float cbv = cb[c];
    const u16* base = xbcr + (size_t)rstart * CONV_DIM + c;
    float w0 = (t0 >= 3) ? bf2f(base[-3 * CONV_DIM]) : 0.f;
    float w1 = (t0 >= 2) ? bf2f(base[-2 * CONV_DIM]) : 0.f;
    float w2 = (t0 >= 1) ? bf2f(base[-1 * CONV_DIM]) : 0.f;
    const bool isx = (cg < 24);
    #pragma unroll
    for (int r = 0; r < 16; r++) {
        float w3 = bf2f(base[r * CONV_DIM]);
        float acc = cbv + w0*c0 + w1*c1 + w2*c2 + w3*c3;
        float val = acc / (1.f + expf(-acc));
        if (isx) {
            T[rg*16 + r][col] = val;
        } else {
            bc[(size_t)(rstart + r) * 128 + (c - D_INNER)] = f2bf(val);
        }
        w0 = w1; w1 = w2; w2 = w3;
    }
    if (!isx) return;
    __syncthreads();
    const int p = tid >> 2, s0 = (tid & 3) * 16;
    size_t tile = (size_t)(((rc >> 5) * NHEADS + cg) * NCHUNK + (rc & 31));
    size_t obase = tile * 4096 + p * 64 + s0;
    u16x8 ph[2];
    #pragma unroll
    for (int j = 0; j < 16; j++)
        ph[j >> 3][j & 7] = f2bf(T[s0 + j][p]);
    *(u16x8*)(xT + obase)     = ph[0];
    *(u16x8*)(xT + obase + 8) = ph[1];
}

// single-bf16 64x64x64 GEMM helper: 1 MFMA per fragment.
__device__ __forceinline__ void gemm1(const u16* rA, const u16* rW,
                                      int ar0, int wr0, int lq, f32x4 acc[2][2])
{
    #pragma unroll
    for (int kk = 0; kk < 2; kk++) {
        const int khs = kk * 4 + lq;
        const int ab = khs * 512 + ((ar0 & 0x38) | ((ar0 ^ khs) & 7)) * 8;
        const int wb = khs * 512 + ((wr0 & 0x38) | ((wr0 ^ khs) & 7)) * 8;
        bf16x8 ah[2], wh[2];
        #pragma unroll
        for (int f = 0; f < 2; f++) {
            ah[f] = *(const bf16x8*)(rA + ab + f * 128);
            wh[f] = *(const bf16x8*)(rW + wb + f * 128);
        }
        #pragma unroll
        for (int fr = 0; fr < 2; fr++)
            #pragma unroll
            for (int fc = 0; fc < 2; fc++)
                acc[fr][fc] = __builtin_amdgcn_mfma_f32_16x16x32_bf16(
                    ah[fr], wh[fc], acc[fr][fc], 0, 0, 0);
    }
}

// chunk state (dir = blockIdx.z): -> hloc bf16
__global__ __launch_bounds__(256)
void chunk_state_kernel(const u16* __restrict__ xTb, const u16* __restrict__ bcb,
                        const float* __restrict__ lab, const float* __restrict__ dtbb,
                        u16* __restrict__ hlocb)
{
    const int dir = blockIdx.z;
    const u16* xT = xTb + (size_t)dir * NROWS * D_INNER;
    const u16* bc = bcb + (size_t)dir * NROWS * 128;
    const float* la  = lab  + (size_t)dir * NROWS * NHEADS;
    const float* dtb = dtbb + (size_t)dir * NROWS * NHEADS;
    u16* hloc = hlocb + (size_t)dir * HLOC_SZ;

    __shared__ alignas(16) u16 lA[4096];
    __shared__ alignas(16) u16 lW[4096];
    __shared__ float la_sh[64], w_sh[64];
    const int bh = blockIdx.x, c = blockIdx.y;
    const int b = bh / NHEADS, h = bh - b * NHEADS;
    const int row0 = b * SEQLEN + c * Q;
    const size_t tile = (size_t)(bh * NCHUNK + c);
    const int tid = threadIdx.x;

    if (tid < 64) la_sh[tid] = la[(size_t)(row0 + tid) * NHEADS + h];
    __syncthreads();
    if (tid < 64)
        w_sh[tid] = expf(la_sh[63] - la_sh[tid]) * dtb[(size_t)(row0 + tid) * NHEADS + h];
    {
        const int kh = tid & 7, rr = tid >> 3;
        #pragma unroll
        for (int cc = 0; cc < 2; cc++) {
            int row = rr + cc * 32;
            int lws = kh * 512 + ((row & 0x38) | ((row ^ kh) & 7)) * 8;
            *(u16x8*)(lA + lws) = *(const u16x8*)(xT + tile * 4096 + row * 64 + kh * 8);
        }
    }
    __syncthreads();
    {
        const int n = tid & 63, sg = tid >> 6;
        #pragma unroll
        for (int i = 0; i < 16; i++) {
            int s = sg + i * 4;
            float bv = bf2f(bc[(size_t)(row0 + s) * 128 + n]);
            float v = bv * w_sh[s];
            int addr = (s >> 3) * 512 + ((n & 0x38) | ((n ^ (s >> 3)) & 7)) * 8 + (s & 7);
            lW[addr] = f2bf(v);
        }
    }
    __syncthreads();
    const int lane = tid & 63, wid = tid >> 6;
    const int wm = wid >> 1, wn = wid & 1;
    const int l15 = lane & 15, lq = lane >> 4;
    f32x4 acc[2][2];
    const f32x4 z4 = {0.f, 0.f, 0.f, 0.f};
    acc[0][0] = z4; acc[0][1] = z4; acc[1][0] = z4; acc[1][1] = z4;
    gemm1(lA, lW, wm * 32 + l15, wn * 32 + l15, lq, acc);
    #pragma unroll
    for (int fr = 0; fr < 2; fr++)
        #pragma unroll
        for (int fc = 0; fc < 2; fc++)
            #pragma unroll
            for (int r = 0; r < 4; r++) {
                int p = wm * 32 + fr * 16 + lq * 4 + r;
                int n = wn * 32 + fc * 16 + l15;
                hloc[tile * 4096 + p * 64 + n] = f2bf(acc[fr][fc][r]);
            }
}

// in-place sequential fold over bf16 states (dir = blockIdx.z)
__global__ __launch_bounds__(256)
void combine_kernel(u16* __restrict__ hlocb, const float* __restrict__ lab)
{
    const int dir = blockIdx.z;
    u16* hloc = hlocb + (size_t)dir * HLOC_SZ;
    const float* la = lab + (size_t)dir * NROWS * NHEADS;
    const int bh = blockIdx.x;
    const int b = bh / NHEADS, h = bh - b * NHEADS;
    const int off = blockIdx.y * 256 + threadIdx.x;
    float run = 0.f;
    for (int c = 0; c < NCHUNK; c++) {
        u16* ptr = hloc + ((size_t)(bh * NCHUNK + c)) * 4096 + off;
        float sv = bf2f(*ptr);
        *ptr = f2bf(run);
        float cd = expf(la[(size_t)(b * SEQLEN + c * Q + Q - 1) * NHEADS + h]);
        run = fmaf(run, cd, sv);
    }
}

// chunk y + fused gate/norm_w/sqsum (dir = blockIdx.z)
__global__ __launch_bounds__(256)
void chunk_y_kernel(const u16* __restrict__ xTb, const u16* __restrict__ bcb,
                    const u16* __restrict__ hlocb, const float* __restrict__ lab,
                    const float* __restrict__ dtbb,
                    const float* __restrict__ Dp0, const float* __restrict__ Dp1,
                    const u16* __restrict__ z16b,
                    const float* __restrict__ nw0, const float* __restrict__ nw1,
                    u16* __restrict__ ygb, float* __restrict__ sqsb)
{
    const int dir = blockIdx.z;
    const u16* xT = xTb + (size_t)dir * NROWS * D_INNER;
    const u16* bc = bcb + (size_t)dir * NROWS * 128;
    const u16* hloc = hlocb + (size_t)dir * HLOC_SZ;
    const float* la  = lab  + (size_t)dir * NROWS * NHEADS;
    const float* dtb = dtbb + (size_t)dir * NROWS * NHEADS;
    const float* Dp = dir ? Dp1 : Dp0;
    const u16* z16 = z16b + (size_t)dir * NROWS * D_INNER;
    const float* norm_w = dir ? nw1 : nw0;
    u16* ygp = ygb + (size_t)dir * NROWS * D_INNER;
    float* sqsum = sqsb + (size_t)dir * NROWS;

    __shared__ alignas(16) u16 r1[4096];
    __shared__ alignas(16) u16 r2[4096];
    __shared__ float la_sh[64], dt_sh[64], ssh[64];
    const int bh = blockIdx.x, c = blockIdx.y;
    const int b = bh / NHEADS, h = bh - b * NHEADS;
    const int row0 = b * SEQLEN + c * Q;
    const size_t tile = (size_t)(bh * NCHUNK + c);
    const int tid = threadIdx.x;
    if (tid < 64) {
        la_sh[tid] = la[(size_t)(row0 + tid) * NHEADS + h];
        dt_sh[tid] = dtb[(size_t)(row0 + tid) * NHEADS + h];
        ssh[tid] = 0.f;
    }
    const int kh = tid & 7, rr = tid >> 3;
    #pragma unroll
    for (int cc = 0; cc < 2; cc++) {
        int row = rr + cc * 32;
        int lws = kh * 512 + ((row & 0x38) | ((row ^ kh) & 7)) * 8;
        *(u16x8*)(r1 + lws) = *(const u16x8*)(bc + (size_t)(row0 + row) * 128 + 64 + kh * 8);
        *(u16x8*)(r2 + lws) = *(const u16x8*)(hloc + tile * 4096 + row * 64 + kh * 8);
    }
    __syncthreads();
    const int lane = tid & 63, wid = tid >> 6;
    const int wm = wid >> 1, wn = wid & 1;
    const int l15 = lane & 15, lq = lane >> 4;
    const int ar0 = wm * 32 + l15, wr0 = wn * 32 + l15;
    const f32x4 z4 = {0.f, 0.f, 0.f, 0.f};
    f32x4 acc2[2][2];
    acc2[0][0] = z4; acc2[0][1] = z4; acc2[1][0] = z4; acc2[1][1] = z4;
    gemm1(r1, r2, ar0, wr0, lq, acc2);
    __syncthreads();
    #pragma unroll
    for (int cc = 0; cc < 2; cc++) {
        int row = rr + cc * 32;
        int lws = kh * 512 + ((row & 0x38) | ((row ^ kh) & 7)) * 8;
        *(u16x8*)(r2 + lws) = *(const u16x8*)(bc + (size_t)(row0 + row) * 128 + kh * 8);
    }
    __syncthreads();
    f32x4 accG[2][2];
    accG[0][0] = z4; accG[0][1] = z4; accG[1][0] = z4; accG[1][1] = z4;
    gemm1(r1, r2, ar0, wr0, lq, accG);
    __syncthreads();
    const float Dph = Dp[h];
    #pragma unroll
    for (int fr = 0; fr < 2; fr++)
        #pragma unroll
        for (int fc = 0; fc < 2; fc++)
            #pragma unroll
            for (int r = 0; r < 4; r++) {
                int t = wm * 32 + fr * 16 + lq * 4 + r;
                int s = wn * 32 + fc * 16 + l15;
                float v = 0.f;
                if (s <= t) v = accG[fr][fc][r] * expf(la_sh[t] - la_sh[s]) * dt_sh[s];
                if (s == t) v += Dph;
                int addr = (s >> 3) * 512 + ((t & 0x38) | ((t ^ (s >> 3)) & 7)) * 8 + (s & 7);
                r1[addr] = f2bf(v);
            }
    #pragma unroll
    for (int cc = 0; cc < 2; cc++) {
        int row = rr + cc * 32;
        int lws = kh * 512 + ((row & 0x38) | ((row ^ kh) & 7)) * 8;
        *(u16x8*)(r2 + lws) = *(const u16x8*)(xT + tile * 4096 + row * 64 + kh * 8);
    }
    __syncthreads();
    f32x4 acc1[2][2];
    acc1[0][0] = z4; acc1[0][1] = z4; acc1[1][0] = z4; acc1[1][1] = z4;
    gemm1(r1, r2, ar0, wr0, lq, acc1);
    #pragma unroll
    for (int fr = 0; fr < 2; fr++)
        #pragma unroll
        for (int r = 0; r < 4; r++) {
            int t = wm * 32 + fr * 16 + lq * 4 + r;
            size_t row = row0 + t;
            float Et = expf(la_sh[t]);
            float s2 = 0.f;
            #pragma unroll
            for (int fc = 0; fc < 2; fc++) {
                int hp = h * 64 + wn * 32 + fc * 16 + l15;
                float yv = acc1[fr][fc][r] + Et * acc2[fr][fc][r];
                float zv = bf2f(z16[row * D_INNER + hp]);
                float gv = yv * (zv / (1.f + expf(-zv)));
                s2 = fmaf(gv, gv, s2);
                float gn = gv * norm_w[hp];
                ygp[row * D_INNER + hp] = f2bf(gn);
            }
            s2 += __shfl_xor(s2, 1);
            s2 += __shfl_xor(s2, 2);
            s2 += __shfl_xor(s2, 4);
            s2 += __shfl_xor(s2, 8);
            if (l15 == 0) atomicAdd(&ssh[t], s2);
        }
    __syncthreads();
    if (tid < 64) atomicAdd(&sqsum[row0 + tid], ssh[tid]);
}

// merged big-out: C[m] = s0[m]*(yg0[m]@wd0) + s1[fm]*(yg1[fm]@wd1) + bias + x[m]
// dual accumulators, two K=1536 phases; global_load_lds staging. grid (6, 64) x 256.
__global__ __launch_bounds__(256, 2)
void mfma_gemm_out(const u16* __restrict__ ygb, const u16* __restrict__ wdb,
                   const int* __restrict__ lengths, const float* __restrict__ sqs,
                   const float* __restrict__ bias, const float* __restrict__ x,
                   float* __restrict__ C)
{
    __shared__ alignas(16) u16 lds[2 * 2 * 4096];
    const int tid = threadIdx.x;
    int bxr = blockIdx.x, byr = blockIdx.y;
    xcd_remap(bxr, byr);
    const int m0 = byr * 128;
    const int n0 = bxr * 128;
    const int lane = tid & 63;
    const int wid = tid >> 6;
    const int wm = wid >> 1, wn = wid & 1;

    int aoffs0[2], aoffs1[2], woffs[2], ldsoff[2];
    #pragma unroll
    for (int i = 0; i < 2; i++) {
        int rsw = i * 64 + lane;
        int r = (rsw & 0x78) | ((rsw & 7) ^ ((wid << 1) & 7));
        aoffs0[i] = (m0 + r) * D_INNER + wid * 8;
        aoffs1[i] = flip_row(m0 + r, lengths) * D_INNER + wid * 8;
        int wr = n0 + r; if (wr >= D_MODEL) wr = D_MODEL - 1;
        woffs[i] = wr * D_INNER + wid * 8;
        ldsoff[i] = wid * 1024 + i * 512;
    }

    f32x4 acc[2][4][4];
    const f32x4 zero4 = {0.f, 0.f, 0.f, 0.f};
    #pragma unroll
    for (int p = 0; p < 2; p++)
        #pragma unroll
        for (int i = 0; i < 4; i++)
            #pragma unroll
            for (int j = 0; j < 4; j++) acc[p][i][j] = zero4;

    const int l15 = lane & 15, lq = lane >> 4;
    const int arow0 = wm * 64 + l15;
    const int wrow0 = wn * 64 + l15;
    const int abase = lq * 1024 + ((arow0 & 0x78) | ((arow0 ^ (lq << 1)) & 7)) * 8;
    const int wbase = lq * 1024 + ((wrow0 & 0x78) | ((wrow0 ^ (lq << 1)) & 7)) * 8;

    #pragma unroll
    for (int ph = 0; ph < 2; ph++) {
        const u16* A = ygb + (size_t)ph * NROWS * D_INNER;
        const u16* W = wdb + (size_t)ph * D_MODEL * D_INNER;
        const int* ao = ph ? aoffs1 : aoffs0;   // compile-time via unroll
        #pragma unroll
        for (int i = 0; i < 2; i++) {
            gload_lds16(A + (size_t)ao[i], lds + 0 * 4096 + ldsoff[i]);
            gload_lds16(W + (size_t)woffs[i], lds + 1 * 4096 + ldsoff[i]);
        }
        __syncthreads();
        int cur = 0;
        for (int kt = 0; kt < D_INNER; kt += 32) {
            u16* Lc = lds + cur * 8192;
            if (kt + 32 < D_INNER) {
                u16* Ln = lds + (cur ^ 1) * 8192;
                #pragma unroll
                for (int i = 0; i < 2; i++) {
                    gload_lds16(A + (size_t)ao[i] + kt + 32, Ln + 0 * 4096 + ldsoff[i]);
                    gload_lds16(W + (size_t)woffs[i] + kt + 32, Ln + 1 * 4096 + ldsoff[i]);
                }
            }
            bf16x8 ah[4], wv[4];
            #pragma unroll
            for (int f = 0; f < 4; f++) {
                ah[f] = *(const bf16x8*)(Lc + 0 * 4096 + abase + f * 128);
                wv[f] = *(const bf16x8*)(Lc + 1 * 4096 + wbase + f * 128);
            }
            #pragma unroll
            for (int fr = 0; fr < 4; fr++)
                #pragma unroll
                for (int fc = 0; fc < 4; fc++)
                    acc[ph][fr][fc] = __builtin_amdgcn_mfma_f32_16x16x32_bf16(
                        ah[fr], wv[fc], acc[ph][fr][fc], 0, 0, 0);
            __syncthreads();
            cur ^= 1;
        }
    }

    #pragma unroll
    for (int fr = 0; fr < 4; fr++) {
        #pragma unroll
        for (int r = 0; r < 4; r++) {
            int mr = m0 + wm * 64 + fr * 16 + lq * 4 + r;
            int fm = flip_row(mr, lengths);
            float s0 = rsqrtf(sqs[mr] * (1.f / D_INNER) + 1e-5f);
            float s1 = rsqrtf(sqs[NROWS + fm] * (1.f / D_INNER) + 1e-5f);
            #pragma unroll
            for (int fc = 0; fc < 4; fc++) {
                int nn = n0 + wn * 64 + fc * 16 + l15;
                if (nn >= D_MODEL) continue;
                float v = s0 * acc[0][fr][fc][r] + s1 * acc[1][fr][fc][r]
                        + bias[nn] + x[(size_t)mr * D_MODEL + nn];
                C[(size_t)mr * D_MODEL + nn] = v;
            }
        }
    }
}

__global__ __launch_bounds__(256)
void layernorm_kernel(const float* __restrict__ r, const float* __restrict__ gam,
                      const float* __restrict__ bet, float* __restrict__ out)
{
    const int row = blockIdx.x;
    const float* rr = r + (size_t)row * D_MODEL;
    const int tid = threadIdx.x;
    float v[3];
    float s = 0.f, s2 = 0.f;
    #pragma unroll
    for (int i = 0; i < 3; i++) {
        v[i] = rr[tid + i * 256];
        s += v[i];
        s2 = fmaf(v[i], v[i], s2);
    }
    #pragma unroll
    for (int o = 32; o > 0; o >>= 1) { s += __shfl_xor(s, o); s2 += __shfl_xor(s2, o); }
    __shared__ float rs[4], rs2[4];
    if ((tid & 63) == 0) { rs[tid >> 6] = s; rs2[tid >> 6] = s2; }
    __syncthreads();
    float S  = rs[0] + rs[1] + rs[2] + rs[3];
    float S2 = rs2[0] + rs2[1] + rs2[2] + rs2[3];
    float mu  = S * (1.f / D_MODEL);
    float var = S2 * (1.f / D_MODEL) - mu * mu;
    float inv = rsqrtf(var + 1e-5f);
    #pragma unroll
    for (int i = 0; i < 3; i++) {
        int e = tid + i * 256;
        out[(size_t)row * D_MODEL + e] = (v[i] - mu) * inv * gam[e] + bet[e];
    }
}

extern "C" void kernel_launch(void* const* d_in, const int* in_sizes, int n_in,
                              void* d_out, int out_size, void* d_ws, size_t ws_size,
                              hipStream_t stream)
{
    const float* x        = (const float*)d_in[0];
    const int*   lengths  = (const int*)d_in[1];
    const float* in_w[2]    = {(const float*)d_in[2],  (const float*)d_in[10]};
    const float* conv_w[2]  = {(const float*)d_in[3],  (const float*)d_in[11]};
    const float* conv_b[2]  = {(const float*)d_in[4],  (const float*)d_in[12]};
    const float* dt_bias[2] = {(const float*)d_in[5],  (const float*)d_in[13]};
    const float* A_log[2]   = {(const float*)d_in[6],  (const float*)d_in[14]};
    const float* Dp[2]      = {(const float*)d_in[7],  (const float*)d_in[15]};
    const float* norm_w[2]  = {(const float*)d_in[8],  (const float*)d_in[16]};
    const float* out_w[2]   = {(const float*)d_in[9],  (const float*)d_in[17]};
    const float* op_w = (const float*)d_in[18];
    const float* op_b = (const float*)d_in[19];
    const float* ln_g = (const float*)d_in[20];
    const float* ln_b = (const float*)d_in[21];
    float* outp = (float*)d_out;

    // ---- workspace layout (both dirs resident; ~251 MB) ----
    u16*  xq   = (u16*)d_ws;                                  // 8192*768
    u16*  Areg = xq + (size_t)NROWS * D_MODEL;                // max(iwall, yg0+yg1)
    u16*  z16  = Areg + 2 * (size_t)NROWS * D_INNER;          // z0|z1
    u16*  xbreg= z16 + 2 * (size_t)NROWS * D_INNER;           // xb0|xb1 (-> hloc0|hloc1)
    float* la  = (float*)(xbreg + 2 * (size_t)NROWS * CONV_DIM);
    float* dtb = la  + 2 * (size_t)NROWS * NHEADS;
    float* sqs = dtb + 2 * (size_t)NROWS * NHEADS;            // 2*8192
    u16*  xTreg= (u16*)(sqs + 2 * NROWS);                     // xT0|xT1 (-> prep)
    u16*  bc   = xTreg + 2 * (size_t)NROWS * D_INNER;         // bc0|bc1
    float* rbuf= (float*)(bc + 2 * (size_t)NROWS * 128);      // 8192*768 f32

    u16* iwall = Areg;                       // 6448*768 during in_proj
    u16* ygb   = Areg;                       // yg0|yg1 after chunk_y
    u16* xb0   = xbreg;
    u16* xb1   = xbreg + (size_t)NROWS * CONV_DIM;
    u16* z0    = z16;
    u16* z1    = z16 + (size_t)NROWS * D_INNER;
    u16* hlocb = xbreg;                      // hloc0|hloc1 overlay (xb dead)

    // prep overlay on xT region (dead after chunk_y)
    u16* oph  = xTreg;
    u16* owTb = oph + (size_t)D_MODEL * D_INNER;              // owT0|owT1
    u16* wdb  = owTb + 2 * (size_t)D_INNER * D_MODEL;         // wd0|wd1

    size_t need = ((size_t)(rbuf + (size_t)NROWS * D_MODEL) - (size_t)d_ws);
    if (ws_size < need) return;

    // 1-3. converts: x, in_w0, in_w1 -> iwall
    convert_single_kernel<<<(NROWS*D_MODEL/4 + 255)/256, 256, 0, stream>>>(
        x, xq, NROWS*D_MODEL/4);
    convert_single_kernel<<<(D_IN_PROJ*D_MODEL/4 + 255)/256, 256, 0, stream>>>(
        in_w[0], iwall, D_IN_PROJ*D_MODEL/4);
    convert_single_kernel<<<(D_IN_PROJ*D_MODEL/4 + 255)/256, 256, 0, stream>>>(
        in_w[1], iwall + (size_t)D_IN_PROJ*D_MODEL, D_IN_PROJ*D_MODEL/4);
    // 4. merged in_proj (N=6448): dir0 rows m, dir1 rows flip(m); XCD-swizzled
    mfma_gemm<<<dim3(51, 64, 1), 256, 0, stream>>>(
        xq, D_MODEL, iwall, D_MODEL, N_MERGED, D_MODEL, lengths, 1,
        z0, xb0, z1, xb1, nullptr, 0, nullptr, nullptr, nullptr);
    // 5. merged exact dt (both dirs) + sqs zero
    dt_exact_kernel<<<dim3(NROWS/4, 2), 256, 0, stream>>>(
        x, in_w[0] + (size_t)(D_INNER + CONV_DIM) * D_MODEL,
        in_w[1] + (size_t)(D_INNER + CONV_DIM) * D_MODEL, lengths, la, sqs);
    // 6. merged conv + transpose + dt/cumsum
    conv_silu_fused_kernel<<<dim3(27, BATCH*NCHUNK, 2), 256, 0, stream>>>(
        xbreg, conv_w[0], conv_w[1], conv_b[0], conv_b[1],
        xTreg, bc, dt_bias[0], dt_bias[1], A_log[0], A_log[1], dtb, la);
    // 7-9. merged chunked SSD scan
    chunk_state_kernel<<<dim3(BATCH*NHEADS, NCHUNK, 2), 256, 0, stream>>>(
        xTreg, bc, la, dtb, hlocb);
    combine_kernel<<<dim3(BATCH*NHEADS, 16, 2), 256, 0, stream>>>(hlocb, la);
    chunk_y_kernel<<<dim3(BATCH*NHEADS, NCHUNK, 2), 256, 0, stream>>>(
        xTreg, bc, hlocb, la, dtb, Dp[0], Dp[1], z16,
        norm_w[0], norm_w[1], ygb, sqs);
    // 10. merged prep (op_w convert + both out_w transposes)
    prep_outw_kernel<<<NCONV_BLK + 2*NT_BLK, 256, 0, stream>>>(
        op_w, out_w[0], out_w[1], oph, owTb);
    // 11. merged wd GEMMs via z-switch (gy=6: remap self-disables)
    mfma_gemm<<<dim3(12, 6, 2), 256, 0, stream>>>(
        oph, 2*D_MODEL, owTb, D_MODEL, D_INNER, D_MODEL, lengths, 4,
        nullptr, nullptr, nullptr, nullptr, wdb, D_INNER,
        oph + D_MODEL, owTb + (size_t)D_INNER*D_MODEL, wdb + (size_t)D_MODEL*D_INNER);
    // 12. merged big-out (dual accumulators, both dirs; XCD-swizzled)
    mfma_gemm_out<<<dim3(6, 64), 256, 0, stream>>>(
        ygb, wdb, lengths, sqs, op_b, x, rbuf);
    // 13. layernorm -> out
    layernorm_kernel<<<NROWS, 256, 0, stream>>>(rbuf, ln_g, ln_b, outp);
}

// Round 28
// 445.650 us; speedup vs baseline: 1.2440x; 1.2440x over previous
//
#include <hip/hip_runtime.h>
#include <cstdint>
#include <cstddef>

#define D_MODEL   768
#define D_STATE   64
#define D_INNER   1536
#define HEADDIM   64
#define NHEADS    24
#define D_CONV    4
#define CONV_DIM  1664      // D_INNER + 2*D_STATE
#define D_IN_PROJ 3224      // 2*D_INNER + 2*D_STATE + NHEADS
#define N_MERGED  6448      // 2 * D_IN_PROJ
#define BATCH     4
#define SEQLEN    2048
#define NROWS     (BATCH*SEQLEN)   // 8192
#define NCHUNK    32
#define Q         64               // chunk length
#define HLOC_SZ   ((size_t)BATCH*NHEADS*NCHUNK*4096)   // per dir, u16

typedef unsigned short u16;
typedef __attribute__((ext_vector_type(8))) short bf16x8;
typedef __attribute__((ext_vector_type(8))) unsigned short u16x8;
typedef __attribute__((ext_vector_type(4))) float f32x4;

__device__ __forceinline__ int flip_row(int m, const int* __restrict__ lengths) {
    int b = m >> 11;
    int t = m & (SEQLEN - 1);
    int len = lengths[b];
    int ft = (t < len) ? (len - 1 - t) : t;
    return (b << 11) | ft;
}

__device__ __forceinline__ u16 f2bf(float f) {
    unsigned int u = __float_as_uint(f);
    unsigned int r = u + 0x7FFFu + ((u >> 16) & 1u);
    return (u16)(r >> 16);
}
__device__ __forceinline__ float bf2f(u16 h) {
    return __uint_as_float(((unsigned int)h) << 16);
}

// async global->LDS DMA, 16B per lane. LDS dest is wave-uniform base + lane*16.
typedef const __attribute__((address_space(1))) unsigned int gu32;
typedef __attribute__((address_space(3))) unsigned int lu32;
__device__ __forceinline__ void gload_lds16(const u16* g, u16* l) {
    __builtin_amdgcn_global_load_lds((gu32*)g, (lu32*)l, 16, 0, 0);
}

// XCD-aware bijective remap: each XCD owns a contiguous M-band (gy/8 y-tiles,
// A-tiles stay resident in its private L2) and walks x-outer / y-inner so each
// W-tile is fetched once per XCD. Requires gy % 8 == 0 (else identity).
__device__ __forceinline__ void xcd_remap(int& bx, int& by) {
    const int gx = gridDim.x, gy = gridDim.y;
    if ((gy & 7) != 0) return;
    const int yband = gy >> 3;
    int flat = by * gx + bx;
    int xcd = flat & 7;
    int pos = flat >> 3;
    bx = pos / yband;
    by = xcd * yband + (pos % yband);
}

// f32 -> single bf16 array
__global__ __launch_bounds__(256)
void convert_single_kernel(const float* __restrict__ in, u16* __restrict__ hi, int n4)
{
    int i = blockIdx.x * 256 + threadIdx.x;
    if (i >= n4) return;
    float4 v = *(const float4*)(in + (size_t)i * 4);
    ushort4 h;
    h.x = f2bf(v.x); h.y = f2bf(v.y); h.z = f2bf(v.z); h.w = f2bf(v.w);
    *(ushort4*)(hi + (size_t)i * 4) = h;
}

// merged prep: (a) op_w (768x1536) -> single bf16, (b) transpose BOTH out_w
// matrices (768x1536 -> owT_d[1536][768] single bf16)
#define NCONV_BLK 1152    // 768*1536/4/256
#define NT_BLK    288     // 24 x 12 transpose tiles (per dir)
__global__ __launch_bounds__(256)
void prep_outw_kernel(const float* __restrict__ op_w,
                      const float* __restrict__ ow0, const float* __restrict__ ow1,
                      u16* __restrict__ oph, u16* __restrict__ owTb)
{
    const int bid = blockIdx.x;
    const int tid = threadIdx.x;
    if (bid < NCONV_BLK) {
        int i = bid * 256 + tid;
        float4 v = *(const float4*)(op_w + (size_t)i * 4);
        ushort4 h;
        h.x = f2bf(v.x); h.y = f2bf(v.y); h.z = f2bf(v.z); h.w = f2bf(v.w);
        *(ushort4*)(oph + (size_t)i * 4) = h;
        return;
    }
    __shared__ float T[64][65];
    const int t = bid - NCONV_BLK;
    const int dir = t / NT_BLK;
    const int tb  = t % NT_BLK;
    const float* ow = dir ? ow1 : ow0;
    u16* owTh = owTb + (size_t)dir * D_INNER * D_MODEL;
    const int e0 = (tb % 24) * 64;
    const int d0 = (tb / 24) * 64;
    const int col = tid & 63, rg = tid >> 6;
    #pragma unroll
    for (int i = 0; i < 16; i++) {
        int r = rg + i * 4;
        T[r][col] = ow[(size_t)(d0 + r) * D_INNER + e0 + col];
    }
    __syncthreads();
    const int er = tid >> 2, dc0 = (tid & 3) * 16;
    u16x8 ph[2];
    #pragma unroll
    for (int j = 0; j < 16; j++)
        ph[j >> 3][j & 7] = f2bf(T[dc0 + j][er]);
    size_t obase = (size_t)(e0 + er) * D_MODEL + d0 + dc0;
    *(u16x8*)(owTh + obase)     = ph[0];
    *(u16x8*)(owTh + obase + 8) = ph[1];
}

// ---------- single-bf16 MFMA GEMM, BK=32, DOUBLE-BUFFERED LDS ----------
// 128x128 tile, 256 threads = 4 waves (2x2), 4x4 16x16 frags/wave.
// Staging via global_load_lds, ROW-MAJOR LDS tile [row][kslot] where slot s of
// row r holds k-group s^(r&3): 4-lane groups read 64B-contiguous global (one
// row), LDS dest linear; MFMA reads at row*32 + (lq^(row&3))*8 (bank-balanced).
// mode 1: merged in_proj split store (N=6448)
// mode 4: Cp[m*ldc+nn] = bf16(acc); blockIdx.z==1 switches to (A2,W2,Cp2)
__global__ __launch_bounds__(256, 4)
void mfma_gemm(const u16* __restrict__ A, int lda,
               const u16* __restrict__ W, int ldw,
               int N, int K, const int* __restrict__ lengths, int mode,
               u16* __restrict__ z0, u16* __restrict__ xb0,
               u16* __restrict__ z1, u16* __restrict__ xb1,
               u16* __restrict__ Cp, int ldc,
               const u16* __restrict__ A2, const u16* __restrict__ W2,
               u16* __restrict__ Cp2)
{
    if (blockIdx.z == 1) { A = A2; W = W2; Cp = Cp2; }
    __shared__ alignas(16) u16 lds[2 * 2 * 4096];   // [buf][matrix][4096]
    const int tid = threadIdx.x;
    int bxr = blockIdx.x, byr = blockIdx.y;
    xcd_remap(bxr, byr);
    const int m0 = byr * 128;
    const int n0 = bxr * 128;
    const int lane = tid & 63;
    const int wv = tid >> 6;
    const int wm = wv >> 1, wn = wv & 1;

    // coalesced staging: lane l -> (row = wv*32+i*16+(l>>2), kg=(l&3)^((l>>2)&3))
    int aoffs[2], woffs[2], ldsoff[2];
    #pragma unroll
    for (int i = 0; i < 2; i++) {
        int row = wv * 32 + i * 16 + (lane >> 2);
        int kg  = (lane & 3) ^ ((lane >> 2) & 3);
        aoffs[i] = (m0 + row) * lda + kg * 8;
        int wr = n0 + row; if (wr >= N) wr = N - 1;
        woffs[i] = wr * ldw + kg * 8;
        ldsoff[i] = wv * 1024 + i * 512;   // u16 units; wave-uniform
    }

    f32x4 acc[4][4];
    const f32x4 zero4 = {0.f, 0.f, 0.f, 0.f};
    #pragma unroll
    for (int i = 0; i < 4; i++)
        #pragma unroll
        for (int j = 0; j < 4; j++) acc[i][j] = zero4;

    const int l15 = lane & 15, lq = lane >> 4;
    // row-major read base: row*32 + (lq ^ (row&3))*8 ; fragment f adds 16 rows
    const int abase = (wm * 64 + l15) * 32 + ((lq ^ (l15 & 3)) * 8);
    const int wbase = (wn * 64 + l15) * 32 + ((lq ^ (l15 & 3)) * 8);

    // prologue: DMA tile 0 -> buf0
    #pragma unroll
    for (int i = 0; i < 2; i++) {
        gload_lds16(A + (size_t)aoffs[i], lds + 0 * 4096 + ldsoff[i]);
        gload_lds16(W + (size_t)woffs[i], lds + 1 * 4096 + ldsoff[i]);
    }
    __syncthreads();

    int cur = 0;
    for (int kt = 0; kt < K; kt += 32) {
        u16* Lc = lds + cur * 8192;
        if (kt + 32 < K) {
            u16* Ln = lds + (cur ^ 1) * 8192;
            #pragma unroll
            for (int i = 0; i < 2; i++) {
                gload_lds16(A + (size_t)aoffs[i] + kt + 32, Ln + 0 * 4096 + ldsoff[i]);
                gload_lds16(W + (size_t)woffs[i] + kt + 32, Ln + 1 * 4096 + ldsoff[i]);
            }
        }
        bf16x8 ah[4], wvv[4];
        #pragma unroll
        for (int f = 0; f < 4; f++) {
            ah[f]  = *(const bf16x8*)(Lc + 0 * 4096 + abase + f * 512);
            wvv[f] = *(const bf16x8*)(Lc + 1 * 4096 + wbase + f * 512);
        }
        #pragma unroll
        for (int fr = 0; fr < 4; fr++)
            #pragma unroll
            for (int fc = 0; fc < 4; fc++)
                acc[fr][fc] = __builtin_amdgcn_mfma_f32_16x16x32_bf16(
                    ah[fr], wvv[fc], acc[fr][fc], 0, 0, 0);
        __syncthreads();   // drains vmcnt (incl. global_load_lds) + barrier
        cur ^= 1;
    }

    #pragma unroll
    for (int fr = 0; fr < 4; fr++) {
        int mr[4], fm[4];
        #pragma unroll
        for (int r = 0; r < 4; r++) {
            mr[r] = m0 + wm * 64 + fr * 16 + lq * 4 + r;
            fm[r] = (mode == 1) ? flip_row(mr[r], lengths) : mr[r];
        }
        #pragma unroll
        for (int fc = 0; fc < 4; fc++) {
            const int nn0 = n0 + wn * 64 + fc * 16 + l15;
            if (nn0 >= N) continue;
            #pragma unroll
            for (int r = 0; r < 4; r++) {
                float v = acc[fr][fc][r];
                if (mode == 1) {
                    int nn = nn0;
                    if (nn < D_INNER)
                        z0[(size_t)mr[r] * D_INNER + nn] = f2bf(v);
                    else if (nn < D_INNER + CONV_DIM)
                        xb0[(size_t)mr[r] * CONV_DIM + (nn - D_INNER)] = f2bf(v);
                    else if (nn >= D_IN_PROJ) {
                        int l2 = nn - D_IN_PROJ;
                        if (l2 < D_INNER)
                            z1[(size_t)fm[r] * D_INNER + l2] = f2bf(v);
                        else if (l2 < D_INNER + CONV_DIM)
                            xb1[(size_t)fm[r] * CONV_DIM + (l2 - D_INNER)] = f2bf(v);
                        // dt cols of either dir: dt_exact covers
                    }
                } else {  // mode 4
                    Cp[(size_t)mr[r] * ldc + nn0] = f2bf(v);
                }
            }
        }
    }
}

// merged exact fp32 dt_raw for both dirs; also zeroes sqsum
// grid (2048, 2) x 256
__global__ __launch_bounds__(256)
void dt_exact_kernel(const float* __restrict__ x,
                     const float* __restrict__ wdt0, const float* __restrict__ wdt1,
                     const int* __restrict__ lengths,
                     float* __restrict__ la, float* __restrict__ sqsum)
{
    const int dir = blockIdx.y;
    const float* wdt = dir ? wdt1 : wdt0;
    float* lad = la + (size_t)dir * NROWS * NHEADS;
    float* sqd = sqsum + (size_t)dir * NROWS;
    const int wv = threadIdx.x >> 6, lane = threadIdx.x & 63;
    const int row = blockIdx.x * 4 + wv;
    int grow = dir ? flip_row(row, lengths) : row;
    const float* xr = x + (size_t)grow * D_MODEL;
    float xv[12];
    #pragma unroll
    for (int k = 0; k < 12; k++) xv[k] = xr[k * 64 + lane];
    if (lane == 1) sqd[row] = 0.f;
    for (int c = 0; c < NHEADS; c++) {
        const float* wr = wdt + (size_t)c * D_MODEL;
        float acc = 0.f;
        #pragma unroll
        for (int k = 0; k < 12; k++) acc = fmaf(xv[k], wr[k * 64 + lane], acc);
        #pragma unroll
        for (int o = 32; o > 0; o >>= 1) acc += __shfl_xor(acc, o);
        if (lane == 0) lad[(size_t)row * NHEADS + c] = acc;
    }
}

// merged conv + silu + per-chunk transpose + (cg==26) dt/cumsum; dir = blockIdx.z
__global__ __launch_bounds__(256)
void conv_silu_fused_kernel(const u16* __restrict__ xbcrb,
                            const float* __restrict__ cw0, const float* __restrict__ cw1,
                            const float* __restrict__ cb0, const float* __restrict__ cb1,
                            u16* __restrict__ xTb, u16* __restrict__ bcb,
                            const float* __restrict__ dtbias0, const float* __restrict__ dtbias1,
                            const float* __restrict__ alog0, const float* __restrict__ alog1,
                            float* __restrict__ dtbb, float* __restrict__ lab)
{
    const int dir = blockIdx.z;
    const u16* xbcr = xbcrb + (size_t)dir * NROWS * CONV_DIM;
    const float* cw = dir ? cw1 : cw0;
    const float* cb = dir ? cb1 : cb0;
    u16* xT = xTb + (size_t)dir * NROWS * D_INNER;
    u16* bc = bcb + (size_t)dir * NROWS * 128;
    const float* dt_bias = dir ? dtbias1 : dtbias0;
    const float* A_log   = dir ? alog1 : alog0;
    float* dtb = dtbb + (size_t)dir * NROWS * NHEADS;
    float* la  = lab  + (size_t)dir * NROWS * NHEADS;

    __shared__ float T[64][65];
    const int cg = blockIdx.x;
    const int rc = blockIdx.y;
    const int tid = threadIdx.x;
    if (cg == 26) {
        const int lane2 = tid & 63, w = tid >> 6;
        const int row0 = rc * 64;
        #pragma unroll
        for (int i = 0; i < 6; i++) {
            int h = w * 6 + i;
            size_t idx = (size_t)(row0 + lane2) * NHEADS + h;
            float v = la[idx] + dt_bias[h];
            float sp = (v > 20.f) ? v : log1pf(expf(v));
            dtb[idx] = sp;
            float dA = sp * (-expf(A_log[h]));
            #pragma unroll
            for (int o = 1; o < 64; o <<= 1) {
                float u = __shfl_up(dA, o);
                if (lane2 >= o) dA += u;
            }
            la[idx] = dA;
        }
        return;
    }
    const int col = tid & 63, rg = tid >> 6;
    const int c = cg * 64 + col;
    const int rstart = rc * 64 + rg * 16;
    const int t0 = rstart & (SEQLEN - 1);
    const float c0 = cw[c*4+0], c1 = cw[c*4+1], c2 = cw[c*4+2], c3 = cw[c*4+3];
    const float cbv = cb[c];
    const u16* base = xbcr + (size_t)rstart * CONV_DIM + c;
    float w0 = (t0 >= 3) ? bf2f(base[-3 * CONV_DIM]) : 0.f;
    float w1 = (t0 >= 2) ? bf2f(base[-2 * CONV_DIM]) : 0.f;
    float w2 = (t0 >= 1) ? bf2f(base[-1 * CONV_DIM]) : 0.f;
    const bool isx = (cg < 24);
    #pragma unroll
    for (int r = 0; r < 16; r++) {
        float w3 = bf2f(base[r * CONV_DIM]);
        float acc = cbv + w0*c0 + w1*c1 + w2*c2 + w3*c3;
        float val = acc / (1.f + expf(-acc));
        if (isx) {
            T[rg*16 + r][col] = val;
        } else {
            bc[(size_t)(rstart + r) * 128 + (c - D_INNER)] = f2bf(val);
        }
        w0 = w1; w1 = w2; w2 = w3;
    }
    if (!isx) return;
    __syncthreads();
    const int p = tid >> 2, s0 = (tid & 3) * 16;
    size_t tile = (size_t)(((rc >> 5) * NHEADS + cg) * NCHUNK + (rc & 31));
    size_t obase = tile * 4096 + p * 64 + s0;
    u16x8 ph[2];
    #pragma unroll
    for (int j = 0; j < 16; j++)
        ph[j >> 3][j & 7] = f2bf(T[s0 + j][p]);
    *(u16x8*)(xT + obase)     = ph[0];
    *(u16x8*)(xT + obase + 8) = ph[1];
}

// single-bf16 64x64x64 GEMM helper: 1 MFMA per fragment.
__device__ __forceinline__ void gemm1(const u16* rA, const u16* rW,
                                      int ar0, int wr0, int lq, f32x4 acc[2][2])
{
    #pragma unroll
    for (int kk = 0; kk < 2; kk++) {
        const int khs = kk * 4 + lq;
        const int ab = khs * 512 + ((ar0 & 0x38) | ((ar0 ^ khs) & 7)) * 8;
        const int wb = khs * 512 + ((wr0 & 0x38) | ((wr0 ^ khs) & 7)) * 8;
        bf16x8 ah[2], wh[2];
        #pragma unroll
        for (int f = 0; f < 2; f++) {
            ah[f] = *(const bf16x8*)(rA + ab + f * 128);
            wh[f] = *(const bf16x8*)(rW + wb + f * 128);
        }
        #pragma unroll
        for (int fr = 0; fr < 2; fr++)
            #pragma unroll
            for (int fc = 0; fc < 2; fc++)
                acc[fr][fc] = __builtin_amdgcn_mfma_f32_16x16x32_bf16(
                    ah[fr], wh[fc], acc[fr][fc], 0, 0, 0);
    }
}

// chunk state (dir = blockIdx.z): -> hloc bf16
__global__ __launch_bounds__(256)
void chunk_state_kernel(const u16* __restrict__ xTb, const u16* __restrict__ bcb,
                        const float* __restrict__ lab, const float* __restrict__ dtbb,
                        u16* __restrict__ hlocb)
{
    const int dir = blockIdx.z;
    const u16* xT = xTb + (size_t)dir * NROWS * D_INNER;
    const u16* bc = bcb + (size_t)dir * NROWS * 128;
    const float* la  = lab  + (size_t)dir * NROWS * NHEADS;
    const float* dtb = dtbb + (size_t)dir * NROWS * NHEADS;
    u16* hloc = hlocb + (size_t)dir * HLOC_SZ;

    __shared__ alignas(16) u16 lA[4096];
    __shared__ alignas(16) u16 lW[4096];
    __shared__ float la_sh[64], w_sh[64];
    const int bh = blockIdx.x, c = blockIdx.y;
    const int b = bh / NHEADS, h = bh - b * NHEADS;
    const int row0 = b * SEQLEN + c * Q;
    const size_t tile = (size_t)(bh * NCHUNK + c);
    const int tid = threadIdx.x;

    if (tid < 64) la_sh[tid] = la[(size_t)(row0 + tid) * NHEADS + h];
    __syncthreads();
    if (tid < 64)
        w_sh[tid] = expf(la_sh[63] - la_sh[tid]) * dtb[(size_t)(row0 + tid) * NHEADS + h];
    {
        const int kh = tid & 7, rr = tid >> 3;
        #pragma unroll
        for (int cc = 0; cc < 2; cc++) {
            int row = rr + cc * 32;
            int lws = kh * 512 + ((row & 0x38) | ((row ^ kh) & 7)) * 8;
            *(u16x8*)(lA + lws) = *(const u16x8*)(xT + tile * 4096 + row * 64 + kh * 8);
        }
    }
    __syncthreads();
    {
        const int n = tid & 63, sg = tid >> 6;
        #pragma unroll
        for (int i = 0; i < 16; i++) {
            int s = sg + i * 4;
            float bv = bf2f(bc[(size_t)(row0 + s) * 128 + n]);
            float v = bv * w_sh[s];
            int addr = (s >> 3) * 512 + ((n & 0x38) | ((n ^ (s >> 3)) & 7)) * 8 + (s & 7);
            lW[addr] = f2bf(v);
        }
    }
    __syncthreads();
    const int lane = tid & 63, wid = tid >> 6;
    const int wm = wid >> 1, wn = wid & 1;
    const int l15 = lane & 15, lq = lane >> 4;
    f32x4 acc[2][2];
    const f32x4 z4 = {0.f, 0.f, 0.f, 0.f};
    acc[0][0] = z4; acc[0][1] = z4; acc[1][0] = z4; acc[1][1] = z4;
    gemm1(lA, lW, wm * 32 + l15, wn * 32 + l15, lq, acc);
    #pragma unroll
    for (int fr = 0; fr < 2; fr++)
        #pragma unroll
        for (int fc = 0; fc < 2; fc++)
            #pragma unroll
            for (int r = 0; r < 4; r++) {
                int p = wm * 32 + fr * 16 + lq * 4 + r;
                int n = wn * 32 + fc * 16 + l15;
                hloc[tile * 4096 + p * 64 + n] = f2bf(acc[fr][fc][r]);
            }
}

// in-place sequential fold over bf16 states (dir = blockIdx.z)
__global__ __launch_bounds__(256)
void combine_kernel(u16* __restrict__ hlocb, const float* __restrict__ lab)
{
    const int dir = blockIdx.z;
    u16* hloc = hlocb + (size_t)dir * HLOC_SZ;
    const float* la = lab + (size_t)dir * NROWS * NHEADS;
    const int bh = blockIdx.x;
    const int b = bh / NHEADS, h = bh - b * NHEADS;
    const int off = blockIdx.y * 256 + threadIdx.x;
    float run = 0.f;
    for (int c = 0; c < NCHUNK; c++) {
        u16* ptr = hloc + ((size_t)(bh * NCHUNK + c)) * 4096 + off;
        float sv = bf2f(*ptr);
        *ptr = f2bf(run);
        float cd = expf(la[(size_t)(b * SEQLEN + c * Q + Q - 1) * NHEADS + h]);
        run = fmaf(run, cd, sv);
    }
}

// chunk y + fused gate/norm_w/sqsum (dir = blockIdx.z)
__global__ __launch_bounds__(256)
void chunk_y_kernel(const u16* __restrict__ xTb, const u16* __restrict__ bcb,
                    const u16* __restrict__ hlocb, const float* __restrict__ lab,
                    const float* __restrict__ dtbb,
                    const float* __restrict__ Dp0, const float* __restrict__ Dp1,
                    const u16* __restrict__ z16b,
                    const float* __restrict__ nw0, const float* __restrict__ nw1,
                    u16* __restrict__ ygb, float* __restrict__ sqsb)
{
    const int dir = blockIdx.z;
    const u16* xT = xTb + (size_t)dir * NROWS * D_INNER;
    const u16* bc = bcb + (size_t)dir * NROWS * 128;
    const u16* hloc = hlocb + (size_t)dir * HLOC_SZ;
    const float* la  = lab  + (size_t)dir * NROWS * NHEADS;
    const float* dtb = dtbb + (size_t)dir * NROWS * NHEADS;
    const float* Dp = dir ? Dp1 : Dp0;
    const u16* z16 = z16b + (size_t)dir * NROWS * D_INNER;
    const float* norm_w = dir ? nw1 : nw0;
    u16* ygp = ygb + (size_t)dir * NROWS * D_INNER;
    float* sqsum = sqsb + (size_t)dir * NROWS;

    __shared__ alignas(16) u16 r1[4096];
    __shared__ alignas(16) u16 r2[4096];
    __shared__ float la_sh[64], dt_sh[64], ssh[64];
    const int bh = blockIdx.x, c = blockIdx.y;
    const int b = bh / NHEADS, h = bh - b * NHEADS;
    const int row0 = b * SEQLEN + c * Q;
    const size_t tile = (size_t)(bh * NCHUNK + c);
    const int tid = threadIdx.x;
    if (tid < 64) {
        la_sh[tid] = la[(size_t)(row0 + tid) * NHEADS + h];
        dt_sh[tid] = dtb[(size_t)(row0 + tid) * NHEADS + h];
        ssh[tid] = 0.f;
    }
    const int kh = tid & 7, rr = tid >> 3;
    #pragma unroll
    for (int cc = 0; cc < 2; cc++) {
        int row = rr + cc * 32;
        int lws = kh * 512 + ((row & 0x38) | ((row ^ kh) & 7)) * 8;
        *(u16x8*)(r1 + lws) = *(const u16x8*)(bc + (size_t)(row0 + row) * 128 + 64 + kh * 8);
        *(u16x8*)(r2 + lws) = *(const u16x8*)(hloc + tile * 4096 + row * 64 + kh * 8);
    }
    __syncthreads();
    const int lane = tid & 63, wid = tid >> 6;
    const int wm = wid >> 1, wn = wid & 1;
    const int l15 = lane & 15, lq = lane >> 4;
    const int ar0 = wm * 32 + l15, wr0 = wn * 32 + l15;
    const f32x4 z4 = {0.f, 0.f, 0.f, 0.f};
    f32x4 acc2[2][2];
    acc2[0][0] = z4; acc2[0][1] = z4; acc2[1][0] = z4; acc2[1][1] = z4;
    gemm1(r1, r2, ar0, wr0, lq, acc2);
    __syncthreads();
    #pragma unroll
    for (int cc = 0; cc < 2; cc++) {
        int row = rr + cc * 32;
        int lws = kh * 512 + ((row & 0x38) | ((row ^ kh) & 7)) * 8;
        *(u16x8*)(r2 + lws) = *(const u16x8*)(bc + (size_t)(row0 + row) * 128 + kh * 8);
    }
    __syncthreads();
    f32x4 accG[2][2];
    accG[0][0] = z4; accG[0][1] = z4; accG[1][0] = z4; accG[1][1] = z4;
    gemm1(r1, r2, ar0, wr0, lq, accG);
    __syncthreads();
    const float Dph = Dp[h];
    #pragma unroll
    for (int fr = 0; fr < 2; fr++)
        #pragma unroll
        for (int fc = 0; fc < 2; fc++)
            #pragma unroll
            for (int r = 0; r < 4; r++) {
                int t = wm * 32 + fr * 16 + lq * 4 + r;
                int s = wn * 32 + fc * 16 + l15;
                float v = 0.f;
                if (s <= t) v = accG[fr][fc][r] * expf(la_sh[t] - la_sh[s]) * dt_sh[s];
                if (s == t) v += Dph;
                int addr = (s >> 3) * 512 + ((t & 0x38) | ((t ^ (s >> 3)) & 7)) * 8 + (s & 7);
                r1[addr] = f2bf(v);
            }
    #pragma unroll
    for (int cc = 0; cc < 2; cc++) {
        int row = rr + cc * 32;
        int lws = kh * 512 + ((row & 0x38) | ((row ^ kh) & 7)) * 8;
        *(u16x8*)(r2 + lws) = *(const u16x8*)(xT + tile * 4096 + row * 64 + kh * 8);
    }
    __syncthreads();
    f32x4 acc1[2][2];
    acc1[0][0] = z4; acc1[0][1] = z4; acc1[1][0] = z4; acc1[1][1] = z4;
    gemm1(r1, r2, ar0, wr0, lq, acc1);
    #pragma unroll
    for (int fr = 0; fr < 2; fr++)
        #pragma unroll
        for (int r = 0; r < 4; r++) {
            int t = wm * 32 + fr * 16 + lq * 4 + r;
            size_t row = row0 + t;
            float Et = expf(la_sh[t]);
            float s2 = 0.f;
            #pragma unroll
            for (int fc = 0; fc < 2; fc++) {
                int hp = h * 64 + wn * 32 + fc * 16 + l15;
                float yv = acc1[fr][fc][r] + Et * acc2[fr][fc][r];
                float zv = bf2f(z16[row * D_INNER + hp]);
                float gv = yv * (zv / (1.f + expf(-zv)));
                s2 = fmaf(gv, gv, s2);
                float gn = gv * norm_w[hp];
                ygp[row * D_INNER + hp] = f2bf(gn);
            }
            s2 += __shfl_xor(s2, 1);
            s2 += __shfl_xor(s2, 2);
            s2 += __shfl_xor(s2, 4);
            s2 += __shfl_xor(s2, 8);
            if (l15 == 0) atomicAdd(&ssh[t], s2);
        }
    __syncthreads();
    if (tid < 64) atomicAdd(&sqsum[row0 + tid], ssh[tid]);
}

// merged big-out: C[m] = s0[m]*(yg0[m]@wd0) + s1[fm]*(yg1[fm]@wd1) + bias + x[m]
// dual accumulators, two K=1536 phases; coalesced global_load_lds staging.
__global__ __launch_bounds__(256, 2)
void mfma_gemm_out(const u16* __restrict__ ygb, const u16* __restrict__ wdb,
                   const int* __restrict__ lengths, const float* __restrict__ sqs,
                   const float* __restrict__ bias, const float* __restrict__ x,
                   float* __restrict__ C)
{
    __shared__ alignas(16) u16 lds[2 * 2 * 4096];
    const int tid = threadIdx.x;
    int bxr = blockIdx.x, byr = blockIdx.y;
    xcd_remap(bxr, byr);
    const int m0 = byr * 128;
    const int n0 = bxr * 128;
    const int lane = tid & 63;
    const int wv = tid >> 6;
    const int wm = wv >> 1, wn = wv & 1;

    int aoffs0[2], aoffs1[2], woffs[2], ldsoff[2];
    #pragma unroll
    for (int i = 0; i < 2; i++) {
        int row = wv * 32 + i * 16 + (lane >> 2);
        int kg  = (lane & 3) ^ ((lane >> 2) & 3);
        aoffs0[i] = (m0 + row) * D_INNER + kg * 8;
        aoffs1[i] = flip_row(m0 + row, lengths) * D_INNER + kg * 8;
        int wr = n0 + row; if (wr >= D_MODEL) wr = D_MODEL - 1;
        woffs[i] = wr * D_INNER + kg * 8;
        ldsoff[i] = wv * 1024 + i * 512;
    }

    f32x4 acc[2][4][4];
    const f32x4 zero4 = {0.f, 0.f, 0.f, 0.f};
    #pragma unroll
    for (int p = 0; p < 2; p++)
        #pragma unroll
        for (int i = 0; i < 4; i++)
            #pragma unroll
            for (int j = 0; j < 4; j++) acc[p][i][j] = zero4;

    const int l15 = lane & 15, lq = lane >> 4;
    const int abase = (wm * 64 + l15) * 32 + ((lq ^ (l15 & 3)) * 8);
    const int wbase = (wn * 64 + l15) * 32 + ((lq ^ (l15 & 3)) * 8);

    #pragma unroll
    for (int ph = 0; ph < 2; ph++) {
        const u16* A = ygb + (size_t)ph * NROWS * D_INNER;
        const u16* W = wdb + (size_t)ph * D_MODEL * D_INNER;
        const int* ao = ph ? aoffs1 : aoffs0;   // compile-time via unroll
        #pragma unroll
        for (int i = 0; i < 2; i++) {
            gload_lds16(A + (size_t)ao[i], lds + 0 * 4096 + ldsoff[i]);
            gload_lds16(W + (size_t)woffs[i], lds + 1 * 4096 + ldsoff[i]);
        }
        __syncthreads();
        int cur = 0;
        for (int kt = 0; kt < D_INNER; kt += 32) {
            u16* Lc = lds + cur * 8192;
            if (kt + 32 < D_INNER) {
                u16* Ln = lds + (cur ^ 1) * 8192;
                #pragma unroll
                for (int i = 0; i < 2; i++) {
                    gload_lds16(A + (size_t)ao[i] + kt + 32, Ln + 0 * 4096 + ldsoff[i]);
                    gload_lds16(W + (size_t)woffs[i] + kt + 32, Ln + 1 * 4096 + ldsoff[i]);
                }
            }
            bf16x8 ah[4], wvv[4];
            #pragma unroll
            for (int f = 0; f < 4; f++) {
                ah[f]  = *(const bf16x8*)(Lc + 0 * 4096 + abase + f * 512);
                wvv[f] = *(const bf16x8*)(Lc + 1 * 4096 + wbase + f * 512);
            }
            #pragma unroll
            for (int fr = 0; fr < 4; fr++)
                #pragma unroll
                for (int fc = 0; fc < 4; fc++)
                    acc[ph][fr][fc] = __builtin_amdgcn_mfma_f32_16x16x32_bf16(
                        ah[fr], wvv[fc], acc[ph][fr][fc], 0, 0, 0);
            __syncthreads();
            cur ^= 1;
        }
    }

    #pragma unroll
    for (int fr = 0; fr < 4; fr++) {
        #pragma unroll
        for (int r = 0; r < 4; r++) {
            int mr = m0 + wm * 64 + fr * 16 + lq * 4 + r;
            int fm = flip_row(mr, lengths);
            float s0 = rsqrtf(sqs[mr] * (1.f / D_INNER) + 1e-5f);
            float s1 = rsqrtf(sqs[NROWS + fm] * (1.f / D_INNER) + 1e-5f);
            #pragma unroll
            for (int fc = 0; fc < 4; fc++) {
                int nn = n0 + wn * 64 + fc * 16 + l15;
                if (nn >= D_MODEL) continue;
                float v = s0 * acc[0][fr][fc][r] + s1 * acc[1][fr][fc][r]
                        + bias[nn] + x[(size_t)mr * D_MODEL + nn];
                C[(size_t)mr * D_MODEL + nn] = v;
            }
        }
    }
}

__global__ __launch_bounds__(256)
void layernorm_kernel(const float* __restrict__ r, const float* __restrict__ gam,
                      const float* __restrict__ bet, float* __restrict__ out)
{
    const int row = blockIdx.x;
    const float* rr = r + (size_t)row * D_MODEL;
    const int tid = threadIdx.x;
    float v[3];
    float s = 0.f, s2 = 0.f;
    #pragma unroll
    for (int i = 0; i < 3; i++) {
        v[i] = rr[tid + i * 256];
        s += v[i];
        s2 = fmaf(v[i], v[i], s2);
    }
    #pragma unroll
    for (int o = 32; o > 0; o >>= 1) { s += __shfl_xor(s, o); s2 += __shfl_xor(s2, o); }
    __shared__ float rs[4], rs2[4];
    if ((tid & 63) == 0) { rs[tid >> 6] = s; rs2[tid >> 6] = s2; }
    __syncthreads();
    float S  = rs[0] + rs[1] + rs[2] + rs[3];
    float S2 = rs2[0] + rs2[1] + rs2[2] + rs2[3];
    float mu  = S * (1.f / D_MODEL);
    float var = S2 * (1.f / D_MODEL) - mu * mu;
    float inv = rsqrtf(var + 1e-5f);
    #pragma unroll
    for (int i = 0; i < 3; i++) {
        int e = tid + i * 256;
        out[(size_t)row * D_MODEL + e] = (v[i] - mu) * inv * gam[e] + bet[e];
    }
}

extern "C" void kernel_launch(void* const* d_in, const int* in_sizes, int n_in,
                              void* d_out, int out_size, void* d_ws, size_t ws_size,
                              hipStream_t stream)
{
    const float* x        = (const float*)d_in[0];
    const int*   lengths  = (const int*)d_in[1];
    const float* in_w[2]    = {(const float*)d_in[2],  (const float*)d_in[10]};
    const float* conv_w[2]  = {(const float*)d_in[3],  (const float*)d_in[11]};
    const float* conv_b[2]  = {(const float*)d_in[4],  (const float*)d_in[12]};
    const float* dt_bias[2] = {(const float*)d_in[5],  (const float*)d_in[13]};
    const float* A_log[2]   = {(const float*)d_in[6],  (const float*)d_in[14]};
    const float* Dp[2]      = {(const float*)d_in[7],  (const float*)d_in[15]};
    const float* norm_w[2]  = {(const float*)d_in[8],  (const float*)d_in[16]};
    const float* out_w[2]   = {(const float*)d_in[9],  (const float*)d_in[17]};
    const float* op_w = (const float*)d_in[18];
    const float* op_b = (const float*)d_in[19];
    const float* ln_g = (const float*)d_in[20];
    const float* ln_b = (const float*)d_in[21];
    float* outp = (float*)d_out;

    // ---- workspace layout (both dirs resident; ~251 MB) ----
    u16*  xq   = (u16*)d_ws;                                  // 8192*768
    u16*  Areg = xq + (size_t)NROWS * D_MODEL;                // max(iwall, yg0+yg1)
    u16*  z16  = Areg + 2 * (size_t)NROWS * D_INNER;          // z0|z1
    u16*  xbreg= z16 + 2 * (size_t)NROWS * D_INNER;           // xb0|xb1 (-> hloc0|hloc1)
    float* la  = (float*)(xbreg + 2 * (size_t)NROWS * CONV_DIM);
    float* dtb = la  + 2 * (size_t)NROWS * NHEADS;
    float* sqs = dtb + 2 * (size_t)NROWS * NHEADS;            // 2*8192
    u16*  xTreg= (u16*)(sqs + 2 * NROWS);                     // xT0|xT1 (-> prep)
    u16*  bc   = xTreg + 2 * (size_t)NROWS * D_INNER;         // bc0|bc1
    float* rbuf= (float*)(bc + 2 * (size_t)NROWS * 128);      // 8192*768 f32

    u16* iwall = Areg;                       // 6448*768 during in_proj
    u16* ygb   = Areg;                       // yg0|yg1 after chunk_y
    u16* xb0   = xbreg;
    u16* xb1   = xbreg + (size_t)NROWS * CONV_DIM;
    u16* z0    = z16;
    u16* z1    = z16 + (size_t)NROWS * D_INNER;
    u16* hlocb = xbreg;                      // hloc0|hloc1 overlay (xb dead)

    // prep overlay on xT region (dead after chunk_y)
    u16* oph  = xTreg;
    u16* owTb = oph + (size_t)D_MODEL * D_INNER;              // owT0|owT1
    u16* wdb  = owTb + 2 * (size_t)D_INNER * D_MODEL;         // wd0|wd1

    size_t need = ((size_t)(rbuf + (size_t)NROWS * D_MODEL) - (size_t)d_ws);
    if (ws_size < need) return;

    // 1-3. converts: x, in_w0, in_w1 -> iwall
    convert_single_kernel<<<(NROWS*D_MODEL/4 + 255)/256, 256, 0, stream>>>(
        x, xq, NROWS*D_MODEL/4);
    convert_single_kernel<<<(D_IN_PROJ*D_MODEL/4 + 255)/256, 256, 0, stream>>>(
        in_w[0], iwall, D_IN_PROJ*D_MODEL/4);
    convert_single_kernel<<<(D_IN_PROJ*D_MODEL/4 + 255)/256, 256, 0, stream>>>(
        in_w[1], iwall + (size_t)D_IN_PROJ*D_MODEL, D_IN_PROJ*D_MODEL/4);
    // 4. merged in_proj (N=6448): dir0 rows m, dir1 rows flip(m); XCD-swizzled
    mfma_gemm<<<dim3(51, 64, 1), 256, 0, stream>>>(
        xq, D_MODEL, iwall, D_MODEL, N_MERGED, D_MODEL, lengths, 1,
        z0, xb0, z1, xb1, nullptr, 0, nullptr, nullptr, nullptr);
    // 5. merged exact dt (both dirs) + sqs zero
    dt_exact_kernel<<<dim3(NROWS/4, 2), 256, 0, stream>>>(
        x, in_w[0] + (size_t)(D_INNER + CONV_DIM) * D_MODEL,
        in_w[1] + (size_t)(D_INNER + CONV_DIM) * D_MODEL, lengths, la, sqs);
    // 6. merged conv + transpose + dt/cumsum
    conv_silu_fused_kernel<<<dim3(27, BATCH*NCHUNK, 2), 256, 0, stream>>>(
        xbreg, conv_w[0], conv_w[1], conv_b[0], conv_b[1],
        xTreg, bc, dt_bias[0], dt_bias[1], A_log[0], A_log[1], dtb, la);
    // 7-9. merged chunked SSD scan
    chunk_state_kernel<<<dim3(BATCH*NHEADS, NCHUNK, 2), 256, 0, stream>>>(
        xTreg, bc, la, dtb, hlocb);
    combine_kernel<<<dim3(BATCH*NHEADS, 16, 2), 256, 0, stream>>>(hlocb, la);
    chunk_y_kernel<<<dim3(BATCH*NHEADS, NCHUNK, 2), 256, 0, stream>>>(
        xTreg, bc, hlocb, la, dtb, Dp[0], Dp[1], z16,
        norm_w[0], norm_w[1], ygb, sqs);
    // 10. merged prep (op_w convert + both out_w transposes)
    prep_outw_kernel<<<NCONV_BLK + 2*NT_BLK, 256, 0, stream>>>(
        op_w, out_w[0], out_w[1], oph, owTb);
    // 11. merged wd GEMMs via z-switch (gy=6: remap self-disables)
    mfma_gemm<<<dim3(12, 6, 2), 256, 0, stream>>>(
        oph, 2*D_MODEL, owTb, D_MODEL, D_INNER, D_MODEL, lengths, 4,
        nullptr, nullptr, nullptr, nullptr, wdb, D_INNER,
        oph + D_MODEL, owTb + (size_t)D_INNER*D_MODEL, wdb + (size_t)D_MODEL*D_INNER);
    // 12. merged big-out (dual accumulators, both dirs; XCD-swizzled)
    mfma_gemm_out<<<dim3(6, 64), 256, 0, stream>>>(
        ygb, wdb, lengths, sqs, op_b, x, rbuf);
    // 13. layernorm -> out
    layernorm_kernel<<<NROWS, 256, 0, stream>>>(rbuf, ln_g, ln_b, outp);
}